// Round 4
// baseline (191.120 us; speedup 1.0000x reference)
//
#include <hip/hip_runtime.h>
#include <stdint.h>

// x [3,5,32,64,32,32] binary float -> per 32x32 image max(component size, bg count)
// -> sum over 64 patches >> 6 -> float [480].
//
// TWO waves per block (128 thr): 16 WG/CU limit x 2 waves = 32 waves/CU (full
// static occupancy) with 2-wave-granular freeing, so data-dependent union-find
// skew backfills finer than 4-wave blocks at the same static ceiling.
// Each wave: TWO images; lanes 0-31 own image A's rows, lanes 32-63 image B's.
// Waves are fully independent (disjoint LDS slices, no barriers, lockstep).
//
// LOAD: fully coalesced. Load instr j reads words pairBase + j*256 + lane*4
// (contiguous 1 KB per wave per instruction -> 16 cache lines). Each uint4
// packs to a 4-bit nibble; 8 nibbles accumulate into one word W per lane.
// Repack to row-per-lane masks: owner lane L's pixel p=L*32+k sits in instr
// j=L>>3, source lane sl=(L&7)*8+(k>>2), nibble bit k&3.
//
// Runs numbered by segmented 64-lane scan (fg popcount packed in high 16b).
// L[i] = parent(9b) | length/size(<<9). Init writes each run's LENGTH into
// its own slot; all union-find writes preserve the high bits. Edge phase:
// lock-free CAS hooking LARGER ROOT -> SMALLER ROOT (read-current + packed
// CAS); JOINT dual-chain find with path halving + root caches for both
// endpoints. Then 2 rounds of parallel pointer-jumping flatten the forest
// (strided, conflict-free, independent -> pipelined). Count phase: balanced
// strided loop, one read + resolve + atomicAdd(len) per non-root run; roots'
// own lengths are already in place. Max phase reads root slots directly.

#define N_IMGS 30720
#define N_OUT  480
#define WAVES_PER_BLOCK 2
#define IMGS_PER_BLOCK (WAVES_PER_BLOCK * 2)   // 4

// Serial find with path halving, preserving packed high bits on writes.
__device__ __forceinline__ int findH(int* L, int i) {
    for (;;) {
        int v = L[i];
        int p = v & 511;
        if (p == i) return i;
        int g = L[p] & 511;
        if (g == p) return p;
        L[i] = g | (v & ~511);       // halving; keep this run's length bits
        i = g;
    }
}

__global__ __launch_bounds__(128)
void ccl_wave2_kernel(const uint32_t* __restrict__ x, int* __restrict__ maxc) {
    __shared__ int Lbuf[IMGS_PER_BLOCK * 512];   // 8 KiB

    const int lane = threadIdx.x & 63;
    const int wv   = threadIdx.x >> 6;
    const int half = lane >> 5;                  // 0: image A, 1: image B
    const int row  = lane & 31;
    const size_t img = (size_t)blockIdx.x * IMGS_PER_BLOCK + wv * 2 + half;
    int* L = Lbuf + (wv * 2 + half) * 512;

    // ---- coalesced load + nibble pack: 8 x uint4, 1 KB/wave/instr ----
    const size_t pairBase = ((size_t)blockIdx.x * IMGS_PER_BLOCK + wv * 2) * 1024;
    const uint4* wp = (const uint4*)(x + pairBase) + lane;
    uint32_t W = 0;
    #pragma unroll
    for (int j = 0; j < 8; ++j) {
        uint4 q = wp[j * 64];                    // words pairBase + j*256 + lane*4
        uint32_t n = (q.x >> 29) | ((q.y >> 29) << 1)
                   | ((q.z >> 29) << 2) | ((q.w >> 29) << 3);
        W |= n << (4 * j);
    }

    // ---- repack to row-per-lane: 8 shuffles + shifts ----
    const int slBase = (lane & 7) * 8;           // first source lane
    const int jsh    = (lane >> 3) * 4;          // my instr's nibble shift
    uint32_t m = 0;
    #pragma unroll
    for (int t = 0; t < 8; ++t) {
        uint32_t sv = (uint32_t)__shfl((int)W, slBase + t);
        m |= ((sv >> jsh) & 0xFu) << (4 * t);
    }

    // ---- run numbering + fg count: ONE 64-lane inclusive scan, segmented at
    // lane 32. Packed word: low 16 = run count, high 16 = popcount. ----
    uint32_t runStarts = m & ~(m << 1);
    int nruns = __popc(runStarts);
    int packed = nruns | (__popc(m) << 16);
    int scan = packed;
    #pragma unroll
    for (int off = 1; off < 64; off <<= 1) {
        int u = __shfl_up(scan, off);
        if (lane >= off) scan += u;
    }
    const int totalA   = __shfl(scan, 31);
    const int totalAll = __shfl(scan, 63);
    const int myTotal  = half ? (totalAll - totalA) : totalA;
    // low fields never borrow (inclusive scan >= own; half-B scan >= totalA)
    const int base = (scan - packed - (half ? totalA : 0)) & 0xFFFF;
    const int R    = myTotal & 0xFFFF;           // runs in my image
    const int fg   = myTotal >> 16;              // foreground pixels, my image

    // ---- init: each run's slot gets parent=self | its LENGTH << 9 ----
    {
        uint32_t mm = m;
        int idx = base;
        while (mm) {
            int s = __ffs(mm) - 1;
            uint32_t t  = mm + (1u << s);
            uint32_t rm = (t ^ mm) & mm;         // this run's bits
            mm &= ~rm;
            L[idx] = idx | (__popc(rm) << 9);
            ++idx;
        }
    }

    // ---- edges: one per overlap segment with previous row ----
    uint32_t mprev  = __shfl_up(m, 1);
    uint32_t rsPrev = __shfl_up(runStarts, 1);
    int      bPrev  = __shfl_up(base, 1);
    if (row == 0) mprev = 0;                 // row 0 of each image
    uint32_t ov  = m & mprev;
    uint32_t ovs = ov & ~(ov << 1);

    int lastA = -1, rootA = -1;              // cache: root of current lower run
    int lastB = -1, rootB = -1;              // cache: root of current upper run
    while (ovs) {
        int c = __ffs(ovs) - 1; ovs &= ovs - 1;
        uint32_t mc = (2u << c) - 1;         // bits 0..c (c=31 -> all ones)
        int a = base  + __popc(runStarts & mc) - 1;
        int b = bPrev + __popc(rsPrev    & mc) - 1;

        int ra = (a == lastA) ? rootA : a;   // reuse merged roots if same run
        int rb = (b == lastB) ? rootB : b;
        // joint dual-chain find: both chains advance 2 levels per iteration;
        // the 4 LDS reads are independent and pipeline in the queue.
        for (;;) {
            int va = L[ra], vb = L[rb];
            int pa = va & 511, pb = vb & 511;
            if (pa == ra && pb == rb) break;
            int ga = L[pa] & 511;            // grandparents (independent)
            int gb = L[pb] & 511;
            if (pa != ra) { L[ra] = ga | (va & ~511); ra = ga; }
            if (pb != rb) { L[rb] = gb | (vb & ~511); rb = gb; }
        }
        while (ra != rb) {                   // hook larger ROOT to smaller
            int hi = ra > rb ? ra : rb;
            int lo = ra ^ rb ^ hi;
            int cur = L[hi];
            if ((cur & 511) == hi) {         // still a root: try packed hook
                int old = atomicCAS(&L[hi], cur, lo | (cur & ~511));
                if (old == cur) { ra = lo; break; }
                cur = old;                   // lost race; chase new parent
            }
            ra = findH(L, cur & 511);
            rb = lo;
        }
        lastA = a; rootA = ra; lastB = b; rootB = ra;
    }
    // wave reconverges here: all unions complete before any lane proceeds.

    // ---- parallel flatten: 2 rounds of pointer jumping over all runs.
    // Strided i -> conflict-free; parent reads cluster at roots -> broadcast.
    // Independent across i within a round -> LDS reads pipeline. ----
    #pragma unroll
    for (int rnd = 0; rnd < 2; ++rnd) {
        for (int i = row; i < R; i += 32) {
            int v = L[i];
            int p = v & 511;
            int g = L[p] & 511;
            if (g != p) L[i] = g | (v & ~511);
        }
    }

    // ---- count: balanced strided loop; non-root runs add their stored
    // length into the root slot (adds never touch low 9 bits). Roots' own
    // lengths are already in place. ----
    for (int i = row; i < R; i += 32) {
        int v = L[i];
        int r = v & 511;
        if (r == i) continue;                // root: nothing to add
        int p = L[r] & 511;                  // verify (broadcast read)
        if (p != r) r = findH(L, p);         // rare deep fallback
        atomicAdd(&L[r], v & ~511);
    }

    // ---- max component size, per image (strided, conflict-free) ----
    int mx = 0;
    for (int i = row; i < R; i += 32) {
        int v = L[i];
        if ((v & 511) == i) mx = max(mx, v >> 9);
    }
    #pragma unroll
    for (int off = 1; off < 32; off <<= 1) mx = max(mx, __shfl_xor(mx, off));

    if (row == 0) maxc[img] = max(mx, 1024 - fg);
}

__global__ __launch_bounds__(64)
void patch_reduce_kernel(const int* __restrict__ maxc, float* __restrict__ out) {
    const int o = blockIdx.x;   // 0..479
    int v = maxc[(size_t)o * 64 + threadIdx.x];
    #pragma unroll
    for (int off = 32; off > 0; off >>= 1)
        v += __shfl_down(v, off);
    if (threadIdx.x == 0) out[o] = (float)(v >> 6);  // integer division by 64
}

extern "C" void kernel_launch(void* const* d_in, const int* in_sizes, int n_in,
                              void* d_out, int out_size, void* d_ws, size_t ws_size,
                              hipStream_t stream) {
    const uint32_t* x = (const uint32_t*)d_in[0];   // float bits; 1.0f>>29 == 1
    float* out = (float*)d_out;
    int* maxc = (int*)d_ws;   // 30720 ints

    ccl_wave2_kernel<<<N_IMGS / IMGS_PER_BLOCK, 128, 0, stream>>>(x, maxc);
    patch_reduce_kernel<<<N_OUT, 64, 0, stream>>>(maxc, out);
}

// Round 5
// 190.787 us; speedup vs baseline: 1.0017x; 1.0017x over previous
//
#include <hip/hip_runtime.h>
#include <stdint.h>

// x [3,5,32,64,32,32] binary float -> per 32x32 image max(component size, bg count)
// -> sum over 64 patches >> 6 -> float [480].
//
// TWO waves per block (128 thr), TWO images per wave: lanes 0-31 own image A's
// rows, lanes 32-63 image B's. Waves independent (disjoint LDS, no barriers).
//
// EXACT SHORT-CIRCUIT: any component <= fg; if fg <= 512 then every component
// <= fg <= 1024-fg = bg count, so the image's answer is exactly 1024-fg and
// ALL union-find work is skipped for it (~50% of images at p=0.5). Since every
// serial phase's wave trip = max over lanes, zeroing a skipped image's masks
// removes its lanes' trips within the wave for free.
//
// LOAD: fully coalesced. Load instr j reads words pairBase + j*256 + lane*4
// (contiguous 1 KB per wave per instruction -> 16 cache lines). Each uint4
// packs to a 4-bit nibble; 8 nibbles accumulate into one word W per lane.
// Repack to row-per-lane masks: owner lane L's pixel p=L*32+k sits in instr
// j=L>>3, source lane sl=(L&7)*8+(k>>2), nibble bit k&3.
//
// Runs numbered by segmented 64-lane scan (fg popcount packed in high 16b).
// L[i] = parent(9b) | length/size(<<9). Init writes each run's LENGTH into
// its own slot; all union-find writes preserve the high bits. Edge phase:
// lock-free CAS hooking LARGER ROOT -> SMALLER ROOT (read-current + packed
// CAS); JOINT dual-chain find with path halving + root caches for both
// endpoints. Then 2 rounds of parallel pointer-jumping flatten the forest.
// Count: balanced strided loop, one read + resolve + atomicAdd(len) per
// non-root run. Max phase reads root slots directly. Wave-lockstep.

#define N_IMGS 30720
#define N_OUT  480
#define WAVES_PER_BLOCK 2
#define IMGS_PER_BLOCK (WAVES_PER_BLOCK * 2)   // 4

// Serial find with path halving, preserving packed high bits on writes.
__device__ __forceinline__ int findH(int* L, int i) {
    for (;;) {
        int v = L[i];
        int p = v & 511;
        if (p == i) return i;
        int g = L[p] & 511;
        if (g == p) return p;
        L[i] = g | (v & ~511);       // halving; keep this run's length bits
        i = g;
    }
}

__global__ __launch_bounds__(128)
void ccl_wave2_kernel(const uint32_t* __restrict__ x, int* __restrict__ maxc) {
    __shared__ int Lbuf[IMGS_PER_BLOCK * 512];   // 8 KiB

    const int lane = threadIdx.x & 63;
    const int wv   = threadIdx.x >> 6;
    const int half = lane >> 5;                  // 0: image A, 1: image B
    const int row  = lane & 31;
    const size_t img = (size_t)blockIdx.x * IMGS_PER_BLOCK + wv * 2 + half;
    int* L = Lbuf + (wv * 2 + half) * 512;

    // ---- coalesced load + nibble pack: 8 x uint4, 1 KB/wave/instr ----
    const size_t pairBase = ((size_t)blockIdx.x * IMGS_PER_BLOCK + wv * 2) * 1024;
    const uint4* wp = (const uint4*)(x + pairBase) + lane;
    uint32_t W = 0;
    #pragma unroll
    for (int j = 0; j < 8; ++j) {
        uint4 q = wp[j * 64];                    // words pairBase + j*256 + lane*4
        uint32_t n = (q.x >> 29) | ((q.y >> 29) << 1)
                   | ((q.z >> 29) << 2) | ((q.w >> 29) << 3);
        W |= n << (4 * j);
    }

    // ---- repack to row-per-lane: 8 shuffles + shifts ----
    const int slBase = (lane & 7) * 8;           // first source lane
    const int jsh    = (lane >> 3) * 4;          // my instr's nibble shift
    uint32_t m = 0;
    #pragma unroll
    for (int t = 0; t < 8; ++t) {
        uint32_t sv = (uint32_t)__shfl((int)W, slBase + t);
        m |= ((sv >> jsh) & 0xFu) << (4 * t);
    }

    // ---- run numbering + fg count: ONE 64-lane inclusive scan, segmented at
    // lane 32. Packed word: low 16 = run count, high 16 = popcount. ----
    uint32_t runStarts = m & ~(m << 1);
    int nruns = __popc(runStarts);
    int packed = nruns | (__popc(m) << 16);
    int scan = packed;
    #pragma unroll
    for (int off = 1; off < 64; off <<= 1) {
        int u = __shfl_up(scan, off);
        if (lane >= off) scan += u;
    }
    const int totalA   = __shfl(scan, 31);
    const int totalAll = __shfl(scan, 63);
    const int myTotal  = half ? (totalAll - totalA) : totalA;
    // low fields never borrow (inclusive scan >= own; half-B scan >= totalA)
    const int base = (scan - packed - (half ? totalA : 0)) & 0xFFFF;
    const int R    = myTotal & 0xFFFF;           // runs in my image
    const int fg   = myTotal >> 16;              // foreground pixels, my image

    // ---- EXACT skip: fg<=512 -> every component <= fg <= 1024-fg = bg.
    // Answer is 1024-fg; kill all CCL trips for this image's lanes. ----
    const bool skip = (fg <= 512);
    const int  Reff = skip ? 0 : R;
    const uint32_t mEff = skip ? 0u : m;

    // ---- init: each run's slot gets parent=self | its LENGTH << 9 ----
    {
        uint32_t mm = mEff;
        int idx = base;
        while (mm) {
            int s = __ffs(mm) - 1;
            uint32_t t  = mm + (1u << s);
            uint32_t rm = (t ^ mm) & mm;         // this run's bits
            mm &= ~rm;
            L[idx] = idx | (__popc(rm) << 9);
            ++idx;
        }
    }

    // ---- edges: one per overlap segment with previous row ----
    uint32_t mprev  = __shfl_up(mEff, 1);
    uint32_t rsPrev = __shfl_up(runStarts, 1);
    int      bPrev  = __shfl_up(base, 1);
    if (row == 0) mprev = 0;                 // row 0 of each image
    uint32_t ov  = mEff & mprev;
    uint32_t ovs = ov & ~(ov << 1);

    int lastA = -1, rootA = -1;              // cache: root of current lower run
    int lastB = -1, rootB = -1;              // cache: root of current upper run
    while (ovs) {
        int c = __ffs(ovs) - 1; ovs &= ovs - 1;
        uint32_t mc = (2u << c) - 1;         // bits 0..c (c=31 -> all ones)
        int a = base  + __popc(runStarts & mc) - 1;
        int b = bPrev + __popc(rsPrev    & mc) - 1;

        int ra = (a == lastA) ? rootA : a;   // reuse merged roots if same run
        int rb = (b == lastB) ? rootB : b;
        // joint dual-chain find: both chains advance 2 levels per iteration;
        // the 4 LDS reads are independent and pipeline in the queue.
        for (;;) {
            int va = L[ra], vb = L[rb];
            int pa = va & 511, pb = vb & 511;
            if (pa == ra && pb == rb) break;
            int ga = L[pa] & 511;            // grandparents (independent)
            int gb = L[pb] & 511;
            if (pa != ra) { L[ra] = ga | (va & ~511); ra = ga; }
            if (pb != rb) { L[rb] = gb | (vb & ~511); rb = gb; }
        }
        while (ra != rb) {                   // hook larger ROOT to smaller
            int hi = ra > rb ? ra : rb;
            int lo = ra ^ rb ^ hi;
            int cur = L[hi];
            if ((cur & 511) == hi) {         // still a root: try packed hook
                int old = atomicCAS(&L[hi], cur, lo | (cur & ~511));
                if (old == cur) { ra = lo; break; }
                cur = old;                   // lost race; chase new parent
            }
            ra = findH(L, cur & 511);
            rb = lo;
        }
        lastA = a; rootA = ra; lastB = b; rootB = ra;
    }
    // wave reconverges here: all unions complete before any lane proceeds.

    // ---- parallel flatten: 2 rounds of pointer jumping over all runs.
    // Strided i -> conflict-free; parent reads cluster at roots -> broadcast.
    // Independent across i within a round -> LDS reads pipeline. ----
    #pragma unroll
    for (int rnd = 0; rnd < 2; ++rnd) {
        for (int i = row; i < Reff; i += 32) {
            int v = L[i];
            int p = v & 511;
            int g = L[p] & 511;
            if (g != p) L[i] = g | (v & ~511);
        }
    }

    // ---- count: balanced strided loop; non-root runs add their stored
    // length into the root slot (adds never touch low 9 bits). Roots' own
    // lengths are already in place. ----
    for (int i = row; i < Reff; i += 32) {
        int v = L[i];
        int r = v & 511;
        if (r == i) continue;                // root: nothing to add
        int p = L[r] & 511;                  // verify (broadcast read)
        if (p != r) r = findH(L, p);         // rare deep fallback
        atomicAdd(&L[r], v & ~511);
    }

    // ---- max component size, per image (strided, conflict-free) ----
    int mx = 0;
    for (int i = row; i < Reff; i += 32) {
        int v = L[i];
        if ((v & 511) == i) mx = max(mx, v >> 9);
    }
    #pragma unroll
    for (int off = 1; off < 32; off <<= 1) mx = max(mx, __shfl_xor(mx, off));

    if (row == 0) maxc[img] = max(mx, 1024 - fg);
}

__global__ __launch_bounds__(64)
void patch_reduce_kernel(const int* __restrict__ maxc, float* __restrict__ out) {
    const int o = blockIdx.x;   // 0..479
    int v = maxc[(size_t)o * 64 + threadIdx.x];
    #pragma unroll
    for (int off = 32; off > 0; off >>= 1)
        v += __shfl_down(v, off);
    if (threadIdx.x == 0) out[o] = (float)(v >> 6);  // integer division by 64
}

extern "C" void kernel_launch(void* const* d_in, const int* in_sizes, int n_in,
                              void* d_out, int out_size, void* d_ws, size_t ws_size,
                              hipStream_t stream) {
    const uint32_t* x = (const uint32_t*)d_in[0];   // float bits; 1.0f>>29 == 1
    float* out = (float*)d_out;
    int* maxc = (int*)d_ws;   // 30720 ints

    ccl_wave2_kernel<<<N_IMGS / IMGS_PER_BLOCK, 128, 0, stream>>>(x, maxc);
    patch_reduce_kernel<<<N_OUT, 64, 0, stream>>>(maxc, out);
}

// Round 6
// 190.759 us; speedup vs baseline: 1.0019x; 1.0001x over previous
//
#include <hip/hip_runtime.h>
#include <stdint.h>

// x [3,5,32,64,32,32] binary float -> per 32x32 image max(component size, bg count)
// -> sum over 64 patches >> 6 -> float [480].
//
// TWO waves per block (128 thr), TWO images per wave: lanes 0-31 own image A's
// rows, lanes 32-63 image B's. Waves independent (disjoint LDS, no barriers).
//
// LOAD: fully coalesced AND fully pipelined. All 8 uint4 loads are staged
// into a statically-indexed q[8] BEFORE any packing, so the compiler emits
// 8 back-to-back global_load_dwordx4 (staged vmcnt waits): ~8 KB per wave in
// flight instead of ~1 KB. (The previous fused load/pack loop compiled to
// VGPR_Count=20 -> loads serialized -> ~3 TB/s read; this is the fix.)
//
// EXACT SHORT-CIRCUIT: any component <= fg; if fg <= 512 then every component
// <= fg <= 1024-fg = bg count, so the image's answer is exactly 1024-fg and
// all union-find work is skipped for it (~50% of images at p=0.5).
//
// Runs numbered by segmented 64-lane scan (fg popcount packed in high 16b).
// L[i] = parent(9b) | length/size(<<9). Init writes each run's LENGTH into
// its own slot; all union-find writes preserve the high bits. Edge phase:
// lock-free CAS hooking LARGER ROOT -> SMALLER ROOT (read-current + packed
// CAS); JOINT dual-chain find with path halving + root caches for both
// endpoints. Then 2 rounds of parallel pointer-jumping flatten the forest.
// Count: balanced strided loop, one read + resolve + atomicAdd(len) per
// non-root run. Max phase reads root slots directly. Wave-lockstep.

#define N_IMGS 30720
#define N_OUT  480
#define WAVES_PER_BLOCK 2
#define IMGS_PER_BLOCK (WAVES_PER_BLOCK * 2)   // 4

// Serial find with path halving, preserving packed high bits on writes.
__device__ __forceinline__ int findH(int* L, int i) {
    for (;;) {
        int v = L[i];
        int p = v & 511;
        if (p == i) return i;
        int g = L[p] & 511;
        if (g == p) return p;
        L[i] = g | (v & ~511);       // halving; keep this run's length bits
        i = g;
    }
}

__global__ __launch_bounds__(128)
void ccl_wave2_kernel(const uint32_t* __restrict__ x, int* __restrict__ maxc) {
    __shared__ int Lbuf[IMGS_PER_BLOCK * 512];   // 8 KiB

    const int lane = threadIdx.x & 63;
    const int wv   = threadIdx.x >> 6;
    const int half = lane >> 5;                  // 0: image A, 1: image B
    const int row  = lane & 31;
    const size_t img = (size_t)blockIdx.x * IMGS_PER_BLOCK + wv * 2 + half;
    int* L = Lbuf + (wv * 2 + half) * 512;

    // ---- coalesced load, ALL loads issued before ANY pack (8 KB/wave MLP) --
    const size_t pairBase = ((size_t)blockIdx.x * IMGS_PER_BLOCK + wv * 2) * 1024;
    const uint4* wp = (const uint4*)(x + pairBase) + lane;
    uint4 q[8];
    #pragma unroll
    for (int j = 0; j < 8; ++j)
        q[j] = wp[j * 64];                       // words pairBase + j*256 + lane*4

    // ---- nibble pack (static indices only; q stays in registers) ----
    uint32_t W = 0;
    #pragma unroll
    for (int j = 0; j < 8; ++j) {
        uint32_t n = (q[j].x >> 29) | ((q[j].y >> 29) << 1)
                   | ((q[j].z >> 29) << 2) | ((q[j].w >> 29) << 3);
        W |= n << (4 * j);
    }

    // ---- repack to row-per-lane: 8 shuffles + shifts ----
    const int slBase = (lane & 7) * 8;           // first source lane
    const int jsh    = (lane >> 3) * 4;          // my instr's nibble shift
    uint32_t m = 0;
    #pragma unroll
    for (int t = 0; t < 8; ++t) {
        uint32_t sv = (uint32_t)__shfl((int)W, slBase + t);
        m |= ((sv >> jsh) & 0xFu) << (4 * t);
    }

    // ---- run numbering + fg count: ONE 64-lane inclusive scan, segmented at
    // lane 32. Packed word: low 16 = run count, high 16 = popcount. ----
    uint32_t runStarts = m & ~(m << 1);
    int nruns = __popc(runStarts);
    int packed = nruns | (__popc(m) << 16);
    int scan = packed;
    #pragma unroll
    for (int off = 1; off < 64; off <<= 1) {
        int u = __shfl_up(scan, off);
        if (lane >= off) scan += u;
    }
    const int totalA   = __shfl(scan, 31);
    const int totalAll = __shfl(scan, 63);
    const int myTotal  = half ? (totalAll - totalA) : totalA;
    // low fields never borrow (inclusive scan >= own; half-B scan >= totalA)
    const int base = (scan - packed - (half ? totalA : 0)) & 0xFFFF;
    const int R    = myTotal & 0xFFFF;           // runs in my image
    const int fg   = myTotal >> 16;              // foreground pixels, my image

    // ---- EXACT skip: fg<=512 -> every component <= fg <= 1024-fg = bg.
    // Answer is 1024-fg; kill all CCL trips for this image's lanes. ----
    const bool skip = (fg <= 512);
    const int  Reff = skip ? 0 : R;
    const uint32_t mEff = skip ? 0u : m;

    // ---- init: each run's slot gets parent=self | its LENGTH << 9 ----
    {
        uint32_t mm = mEff;
        int idx = base;
        while (mm) {
            int s = __ffs(mm) - 1;
            uint32_t t  = mm + (1u << s);
            uint32_t rm = (t ^ mm) & mm;         // this run's bits
            mm &= ~rm;
            L[idx] = idx | (__popc(rm) << 9);
            ++idx;
        }
    }

    // ---- edges: one per overlap segment with previous row ----
    uint32_t mprev  = __shfl_up(mEff, 1);
    uint32_t rsPrev = __shfl_up(runStarts, 1);
    int      bPrev  = __shfl_up(base, 1);
    if (row == 0) mprev = 0;                 // row 0 of each image
    uint32_t ov  = mEff & mprev;
    uint32_t ovs = ov & ~(ov << 1);

    int lastA = -1, rootA = -1;              // cache: root of current lower run
    int lastB = -1, rootB = -1;              // cache: root of current upper run
    while (ovs) {
        int c = __ffs(ovs) - 1; ovs &= ovs - 1;
        uint32_t mc = (2u << c) - 1;         // bits 0..c (c=31 -> all ones)
        int a = base  + __popc(runStarts & mc) - 1;
        int b = bPrev + __popc(rsPrev    & mc) - 1;

        int ra = (a == lastA) ? rootA : a;   // reuse merged roots if same run
        int rb = (b == lastB) ? rootB : b;
        // joint dual-chain find: both chains advance 2 levels per iteration;
        // the 4 LDS reads are independent and pipeline in the queue.
        for (;;) {
            int va = L[ra], vb = L[rb];
            int pa = va & 511, pb = vb & 511;
            if (pa == ra && pb == rb) break;
            int ga = L[pa] & 511;            // grandparents (independent)
            int gb = L[pb] & 511;
            if (pa != ra) { L[ra] = ga | (va & ~511); ra = ga; }
            if (pb != rb) { L[rb] = gb | (vb & ~511); rb = gb; }
        }
        while (ra != rb) {                   // hook larger ROOT to smaller
            int hi = ra > rb ? ra : rb;
            int lo = ra ^ rb ^ hi;
            int cur = L[hi];
            if ((cur & 511) == hi) {         // still a root: try packed hook
                int old = atomicCAS(&L[hi], cur, lo | (cur & ~511));
                if (old == cur) { ra = lo; break; }
                cur = old;                   // lost race; chase new parent
            }
            ra = findH(L, cur & 511);
            rb = lo;
        }
        lastA = a; rootA = ra; lastB = b; rootB = ra;
    }
    // wave reconverges here: all unions complete before any lane proceeds.

    // ---- parallel flatten: 2 rounds of pointer jumping over all runs.
    // Strided i -> conflict-free; parent reads cluster at roots -> broadcast.
    // Independent across i within a round -> LDS reads pipeline. ----
    #pragma unroll
    for (int rnd = 0; rnd < 2; ++rnd) {
        for (int i = row; i < Reff; i += 32) {
            int v = L[i];
            int p = v & 511;
            int g = L[p] & 511;
            if (g != p) L[i] = g | (v & ~511);
        }
    }

    // ---- count: balanced strided loop; non-root runs add their stored
    // length into the root slot (adds never touch low 9 bits). Roots' own
    // lengths are already in place. ----
    for (int i = row; i < Reff; i += 32) {
        int v = L[i];
        int r = v & 511;
        if (r == i) continue;                // root: nothing to add
        int p = L[r] & 511;                  // verify (broadcast read)
        if (p != r) r = findH(L, p);         // rare deep fallback
        atomicAdd(&L[r], v & ~511);
    }

    // ---- max component size, per image (strided, conflict-free) ----
    int mx = 0;
    for (int i = row; i < Reff; i += 32) {
        int v = L[i];
        if ((v & 511) == i) mx = max(mx, v >> 9);
    }
    #pragma unroll
    for (int off = 1; off < 32; off <<= 1) mx = max(mx, __shfl_xor(mx, off));

    if (row == 0) maxc[img] = max(mx, 1024 - fg);
}

__global__ __launch_bounds__(64)
void patch_reduce_kernel(const int* __restrict__ maxc, float* __restrict__ out) {
    const int o = blockIdx.x;   // 0..479
    int v = maxc[(size_t)o * 64 + threadIdx.x];
    #pragma unroll
    for (int off = 32; off > 0; off >>= 1)
        v += __shfl_down(v, off);
    if (threadIdx.x == 0) out[o] = (float)(v >> 6);  // integer division by 64
}

extern "C" void kernel_launch(void* const* d_in, const int* in_sizes, int n_in,
                              void* d_out, int out_size, void* d_ws, size_t ws_size,
                              hipStream_t stream) {
    const uint32_t* x = (const uint32_t*)d_in[0];   // float bits; 1.0f>>29 == 1
    float* out = (float*)d_out;
    int* maxc = (int*)d_ws;   // 30720 ints

    ccl_wave2_kernel<<<N_IMGS / IMGS_PER_BLOCK, 128, 0, stream>>>(x, maxc);
    patch_reduce_kernel<<<N_OUT, 64, 0, stream>>>(maxc, out);
}